// Round 1
// baseline (13715.631 us; speedup 1.0000x reference)
//
#include <hip/hip_runtime.h>

#define EPS 1e-5f

// -------- scatter: for each (edge, dir) a 32-lane group does
//   dir 0: u_acc[rows[e]] += vals[e] * i_emb[cols[e]]
//   dir 1: i_acc[cols[e]] += vals[e] * u_emb[rows[e]]
__global__ __launch_bounds__(256) void scatter_kernel(
    const float* __restrict__ u_emb, const float* __restrict__ i_emb,
    const float* __restrict__ vals, const int* __restrict__ rows,
    const int* __restrict__ cols, float* __restrict__ u_acc,
    float* __restrict__ i_acc, int ne)
{
    long long gid = (long long)blockIdx.x * blockDim.x + threadIdx.x;
    int lane = (int)(gid & 31);
    long long grp = gid >> 5;
    if (grp >= 2LL * ne) return;
    int dir = grp >= ne;
    int e = (int)(dir ? grp - ne : grp);

    float v = vals[e];
    int r = rows[e];
    int c = cols[e];

    const float4* src;
    float* dst;
    if (dir == 0) {
        src = (const float4*)(i_emb + (long long)c * 128);
        dst = u_acc + (long long)r * 128;
    } else {
        src = (const float4*)(u_emb + (long long)r * 128);
        dst = i_acc + (long long)c * 128;
    }
    float4 x = src[lane];
    float* dp = dst + lane * 4;
    unsafeAtomicAdd(dp + 0, v * x.x);
    unsafeAtomicAdd(dp + 1, v * x.y);
    unsafeAtomicAdd(dp + 2, v * x.z);
    unsafeAtomicAdd(dp + 3, v * x.w);
}

// -------- layernorm: one wave (64 lanes) per row of 128 floats.
// out[row] = gamma * (x - m) * rsqrt(var + eps) + beta,  x = emb[row] + acc[row]
__global__ __launch_bounds__(256) void ln_kernel(
    const float* emb, const float* acc,
    const float* __restrict__ gamma, const float* __restrict__ beta,
    float* out, int nrows)
{
    int wave = blockIdx.x * (256 / 64) + (threadIdx.x >> 6);
    int lane = threadIdx.x & 63;
    if (wave >= nrows) return;

    const float2* e2 = (const float2*)(emb + (long long)wave * 128);
    const float2* a2 = (const float2*)(acc + (long long)wave * 128);
    float2 x = e2[lane];
    float2 a = a2[lane];
    x.x += a.x;
    x.y += a.y;

    float s  = x.x + x.y;
    float ss = x.x * x.x + x.y * x.y;
#pragma unroll
    for (int off = 32; off > 0; off >>= 1) {
        s  += __shfl_xor(s, off, 64);
        ss += __shfl_xor(ss, off, 64);
    }
    float m   = s * (1.0f / 128.0f);
    float var = ss * (1.0f / 128.0f) - m * m;
    float inv = rsqrtf(var + EPS);

    float2 g = ((const float2*)gamma)[lane];
    float2 b = ((const float2*)beta)[lane];
    float2 o;
    o.x = g.x * (x.x - m) * inv + b.x;
    o.y = g.y * (x.y - m) * inv + b.y;
    ((float2*)(out + (long long)wave * 128))[lane] = o;
}

extern "C" void kernel_launch(void* const* d_in, const int* in_sizes, int n_in,
                              void* d_out, int out_size, void* d_ws, size_t ws_size,
                              hipStream_t stream)
{
    const float* user_emb = (const float*)d_in[0];
    const float* item_emb = (const float*)d_in[1];
    const float* vals     = (const float*)d_in[2];
    const float* gamma    = (const float*)d_in[3];
    const float* beta     = (const float*)d_in[4];
    const int*   rows     = (const int*)d_in[5];
    const int*   cols     = (const int*)d_in[6];

    const int nu = in_sizes[0] / 128;   // 100000
    const int ni = in_sizes[1] / 128;   // 200000
    const int ne = in_sizes[2];         // 2000000

    float* out   = (float*)d_out;
    float* u_out = out;                       // [nu*128]
    float* i_out = out + (long long)nu * 128; // [ni*128]

    float* u_acc = (float*)d_ws;
    float* i_acc = u_acc + (long long)nu * 128;
    const size_t acc_bytes = (size_t)(nu + ni) * 128 * sizeof(float);

    const long long sthreads = 2LL * ne * 32;       // 128M
    const int sblocks = (int)((sthreads + 255) / 256);
    const int ublocks = (nu + 3) / 4;  // 4 waves/block
    const int iblocks = (ni + 3) / 4;

    // ---- layer 1 ----
    hipMemsetAsync(u_acc, 0, acc_bytes, stream);
    scatter_kernel<<<sblocks, 256, 0, stream>>>(user_emb, item_emb, vals, rows,
                                                cols, u_acc, i_acc, ne);
    ln_kernel<<<ublocks, 256, 0, stream>>>(user_emb, u_acc, gamma, beta, u_out, nu);
    ln_kernel<<<iblocks, 256, 0, stream>>>(item_emb, i_acc, gamma, beta, i_out, ni);

    // ---- layer 2 ---- (inputs are layer-1 outputs living in d_out)
    hipMemsetAsync(u_acc, 0, acc_bytes, stream);
    scatter_kernel<<<sblocks, 256, 0, stream>>>(u_out, i_out, vals, rows,
                                                cols, u_acc, i_acc, ne);
    ln_kernel<<<ublocks, 256, 0, stream>>>(u_out, u_acc, gamma, beta, u_out, nu);
    ln_kernel<<<iblocks, 256, 0, stream>>>(i_out, i_acc, gamma, beta, i_out, ni);
}

// Round 2
// 1328.740 us; speedup vs baseline: 10.3223x; 10.3223x over previous
//
#include <hip/hip_runtime.h>

#define EPS 1e-5f
typedef long long ll;

// ============ CSR build ============
// Buckets: user row r -> bucket r; item col c -> bucket nu + c.
// Combined CSR over nu+ni buckets, 2*ne entries.

__global__ __launch_bounds__(256) void count_kernel(
    const int* __restrict__ rows, const int* __restrict__ cols,
    int* __restrict__ cnt, int ne, int nu)
{
    int e = blockIdx.x * 256 + threadIdx.x;
    if (e >= ne) return;
    atomicAdd(&cnt[rows[e]], 1);
    atomicAdd(&cnt[nu + cols[e]], 1);
}

// Block-level exclusive scan: 1024 elements per block (256 thr x 4).
__global__ __launch_bounds__(256) void scanA(
    const int* __restrict__ cnt, int* __restrict__ rowptr,
    int* __restrict__ blockpart, int n)
{
    __shared__ int sm[256];
    int t = threadIdx.x;
    int base = blockIdx.x * 1024 + t * 4;
    int v[4]; int s = 0;
#pragma unroll
    for (int k = 0; k < 4; k++) {
        int i = base + k;
        v[k] = (i < n) ? cnt[i] : 0;
        s += v[k];
    }
    sm[t] = s; __syncthreads();
    for (int off = 1; off < 256; off <<= 1) {
        int a = (t >= off) ? sm[t - off] : 0;
        __syncthreads();
        sm[t] += a;
        __syncthreads();
    }
    int excl = sm[t] - s;
    if (t == 255) blockpart[blockIdx.x] = sm[255];
    int run = excl;
#pragma unroll
    for (int k = 0; k < 4; k++) {
        int i = base + k;
        if (i < n) rowptr[i] = run;
        run += v[k];
    }
}

// Single-block exclusive scan of block partials (nb <= 512).
__global__ __launch_bounds__(512) void scanB(int* __restrict__ blockpart, int nb)
{
    __shared__ int sm[512];
    int t = threadIdx.x;
    int v = (t < nb) ? blockpart[t] : 0;
    sm[t] = v; __syncthreads();
    for (int off = 1; off < 512; off <<= 1) {
        int a = (t >= off) ? sm[t - off] : 0;
        __syncthreads();
        sm[t] += a;
        __syncthreads();
    }
    if (t < nb) blockpart[t] = sm[t] - v;
}

// Add block offsets; init cursors; write sentinel.
__global__ __launch_bounds__(256) void scanC(
    int* __restrict__ rowptr, const int* __restrict__ blockpart,
    int* __restrict__ cursor, int n, int total)
{
    int i = blockIdx.x * 256 + threadIdx.x;
    if (i < n) {
        int r = rowptr[i] + blockpart[i >> 10];
        rowptr[i] = r;
        cursor[i] = r;
    }
    if (i == 0) rowptr[n] = total;
}

__global__ __launch_bounds__(256) void fill_kernel(
    const int* __restrict__ rows, const int* __restrict__ cols,
    const float* __restrict__ vals, int* __restrict__ cursor,
    int* __restrict__ csr_src, float* __restrict__ csr_w, int ne, int nu)
{
    int e = blockIdx.x * 256 + threadIdx.x;
    if (e >= ne) return;
    int r = rows[e], c = cols[e];
    float v = vals[e];
    int p = atomicAdd(&cursor[r], 1);
    csr_src[p] = c; csr_w[p] = v;
    int q = atomicAdd(&cursor[nu + c], 1);
    csr_src[q] = r; csr_w[q] = v;
}

// ============ gather SpMM + residual + LayerNorm ============
// One 64-lane wave per destination row (global row id g in [first, first+count)).
// g < nu: user row, gathers from src_u_side; else item row, gathers src_i_side.
__global__ __launch_bounds__(256) void gather_ln(
    const float* __restrict__ src_u_side, const float* __restrict__ src_i_side,
    const float* __restrict__ res_u, const float* __restrict__ res_i,
    float* __restrict__ out_u, float* __restrict__ out_i,
    const int* __restrict__ rowptr, const int* __restrict__ csr_src,
    const float* __restrict__ csr_w,
    const float* __restrict__ gamma, const float* __restrict__ beta,
    int nu, int first, int count)
{
    int w = blockIdx.x * 4 + (threadIdx.x >> 6);
    if (w >= count) return;
    int g = first + w;
    int lane = threadIdx.x & 63;

    const float2* src;
    const float2* res;
    float2* outp;
    if (g < nu) {
        src  = (const float2*)src_u_side;
        res  = (const float2*)(res_u + (ll)g * 128);
        outp = (float2*)(out_u + (ll)g * 128);
    } else {
        int k = g - nu;
        src  = (const float2*)src_i_side;
        res  = (const float2*)(res_i + (ll)k * 128);
        outp = (float2*)(out_i + (ll)k * 128);
    }

    int start = rowptr[g];
    int end   = rowptr[g + 1];

    float ax = 0.0f, ay = 0.0f;
    int j = start;
    for (; j + 1 < end; j += 2) {
        int   s0 = csr_src[j],     s1 = csr_src[j + 1];
        float v0 = csr_w[j],       v1 = csr_w[j + 1];
        float2 x0 = src[(ll)s0 * 64 + lane];
        float2 x1 = src[(ll)s1 * 64 + lane];
        ax += v0 * x0.x; ay += v0 * x0.y;
        ax += v1 * x1.x; ay += v1 * x1.y;
    }
    if (j < end) {
        int   s0 = csr_src[j];
        float v0 = csr_w[j];
        float2 x0 = src[(ll)s0 * 64 + lane];
        ax += v0 * x0.x; ay += v0 * x0.y;
    }

    float2 r = res[lane];
    ax += r.x; ay += r.y;

    float s  = ax + ay;
    float ss = ax * ax + ay * ay;
#pragma unroll
    for (int off = 32; off > 0; off >>= 1) {
        s  += __shfl_xor(s, off, 64);
        ss += __shfl_xor(ss, off, 64);
    }
    float m   = s * (1.0f / 128.0f);
    float var = ss * (1.0f / 128.0f) - m * m;
    float inv = rsqrtf(var + EPS);

    float2 gm = ((const float2*)gamma)[lane];
    float2 bt = ((const float2*)beta)[lane];
    float2 o;
    o.x = gm.x * (ax - m) * inv + bt.x;
    o.y = gm.y * (ay - m) * inv + bt.y;
    outp[lane] = o;
}

extern "C" void kernel_launch(void* const* d_in, const int* in_sizes, int n_in,
                              void* d_out, int out_size, void* d_ws, size_t ws_size,
                              hipStream_t stream)
{
    const float* user_emb = (const float*)d_in[0];
    const float* item_emb = (const float*)d_in[1];
    const float* vals     = (const float*)d_in[2];
    const float* gamma    = (const float*)d_in[3];
    const float* beta     = (const float*)d_in[4];
    const int*   rows     = (const int*)d_in[5];
    const int*   cols     = (const int*)d_in[6];

    const int nu = in_sizes[0] / 128;   // 100000
    const int ni = in_sizes[1] / 128;   // 200000
    const int ne = in_sizes[2];         // 2000000
    const int N  = nu + ni;             // buckets
    const int total = 2 * ne;           // CSR entries

    float* dout   = (float*)d_out;
    float* dout_u = dout;                        // final user region
    float* dout_i = dout + (ll)nu * 128;         // item region (also layer-1 item out)

    // ---- workspace layout ----
    const int Npad = ((N + 1024) + 255) & ~255;  // room for sentinel, aligned
    int*   cnt       = (int*)d_ws;               // N
    int*   rowptr    = cnt + Npad;               // N+1
    int*   cursor    = rowptr + Npad;            // N
    int*   blockpart = cursor + Npad;            // <=512
    int*   csr_src   = blockpart + 512;          // total
    float* csr_w     = (float*)(csr_src + total);// total
    float* ws_u      = (float*)(csr_w + total);  // nu*128 floats (layer-1 user out)

    const int eb  = (ne + 255) / 256;
    const int nbA = (N + 1023) / 1024;
    const int nbC = (N + 256) / 256;   // covers sentinel writer (i==0 anyway)

    // ---- build CSR (once; valid for both layers) ----
    hipMemsetAsync(cnt, 0, (size_t)N * sizeof(int), stream);
    count_kernel<<<eb, 256, 0, stream>>>(rows, cols, cnt, ne, nu);
    scanA<<<nbA, 256, 0, stream>>>(cnt, rowptr, blockpart, N);
    scanB<<<1, 512, 0, stream>>>(blockpart, nbA);
    scanC<<<nbC, 256, 0, stream>>>(rowptr, blockpart, cursor, N, total);
    fill_kernel<<<eb, 256, 0, stream>>>(rows, cols, vals, cursor, csr_src, csr_w, ne, nu);

    // ---- layer 1: inputs (user_emb, item_emb) -> (ws_u, dout_i) ----
    {
        int blocks = (N + 3) / 4;
        gather_ln<<<blocks, 256, 0, stream>>>(
            item_emb, user_emb,          // gather sources for u-side / i-side
            user_emb, item_emb,          // residuals
            ws_u, dout_i,                // outputs
            rowptr, csr_src, csr_w, gamma, beta, nu, 0, N);
    }

    // ---- layer 2a: user rows: gather dout_i, residual ws_u -> dout_u ----
    {
        int blocks = (nu + 3) / 4;
        gather_ln<<<blocks, 256, 0, stream>>>(
            dout_i, ws_u,
            ws_u, dout_i,
            dout_u, dout_i,
            rowptr, csr_src, csr_w, gamma, beta, nu, 0, nu);
    }

    // ---- layer 2b: item rows: gather ws_u, residual dout_i -> dout_i (in-place safe) ----
    {
        int blocks = (ni + 3) / 4;
        gather_ln<<<blocks, 256, 0, stream>>>(
            dout_i, ws_u,                // i-side gathers src_i_side = ws_u
            ws_u, dout_i,
            dout_u, dout_i,
            rowptr, csr_src, csr_w, gamma, beta, nu, nu, ni);
    }
}

// Round 3
// 1256.986 us; speedup vs baseline: 10.9115x; 1.0571x over previous
//
#include <hip/hip_runtime.h>

#define EPS 1e-5f
typedef long long ll;
typedef unsigned int uint;

__device__ __forceinline__ uint bf_round(float x) {
    uint u = __float_as_uint(x);
    return (u + 0x7FFFu + ((u >> 16) & 1u)) >> 16;
}
__device__ __forceinline__ uint pack2(float a, float b) {
    return bf_round(a) | (bf_round(b) << 16);
}
__device__ __forceinline__ float unpack_lo(uint u) { return __uint_as_float(u << 16); }
__device__ __forceinline__ float unpack_hi(uint u) { return __uint_as_float(u & 0xFFFF0000u); }

// ---- convert f32 tables -> bf16x2 packed (user then item, contiguous) ----
__global__ __launch_bounds__(256) void to_bf16(
    const float* __restrict__ ue, const float* __restrict__ ie,
    uint4* __restrict__ out, int nuT, int totT)
{
    int t = blockIdx.x * 256 + threadIdx.x;
    if (t >= totT) return;
    const float4* src = (t < nuT) ? (const float4*)(ue + (ll)t * 8)
                                  : (const float4*)(ie + (ll)(t - nuT) * 8);
    float4 f0 = src[0], f1 = src[1];
    uint4 q;
    q.x = pack2(f0.x, f0.y); q.y = pack2(f0.z, f0.w);
    q.z = pack2(f1.x, f1.y); q.w = pack2(f1.z, f1.w);
    out[t] = q;
}

// ============ CSR build ============
__global__ __launch_bounds__(256) void count_kernel(
    const int* __restrict__ rows, const int* __restrict__ cols,
    int* __restrict__ cnt, int ne, int nu)
{
    int e = blockIdx.x * 256 + threadIdx.x;
    if (e >= ne) return;
    atomicAdd(&cnt[rows[e]], 1);
    atomicAdd(&cnt[nu + cols[e]], 1);
}

__global__ __launch_bounds__(256) void scanA(
    const int* __restrict__ cnt, int* __restrict__ rowptr,
    int* __restrict__ blockpart, int n)
{
    __shared__ int sm[256];
    int t = threadIdx.x;
    int base = blockIdx.x * 1024 + t * 4;
    int v[4]; int s = 0;
#pragma unroll
    for (int k = 0; k < 4; k++) {
        int i = base + k;
        v[k] = (i < n) ? cnt[i] : 0;
        s += v[k];
    }
    sm[t] = s; __syncthreads();
    for (int off = 1; off < 256; off <<= 1) {
        int a = (t >= off) ? sm[t - off] : 0;
        __syncthreads();
        sm[t] += a;
        __syncthreads();
    }
    int excl = sm[t] - s;
    if (t == 255) blockpart[blockIdx.x] = sm[255];
    int run = excl;
#pragma unroll
    for (int k = 0; k < 4; k++) {
        int i = base + k;
        if (i < n) rowptr[i] = run;
        run += v[k];
    }
}

__global__ __launch_bounds__(512) void scanB(int* __restrict__ blockpart, int nb)
{
    __shared__ int sm[512];
    int t = threadIdx.x;
    int v = (t < nb) ? blockpart[t] : 0;
    sm[t] = v; __syncthreads();
    for (int off = 1; off < 512; off <<= 1) {
        int a = (t >= off) ? sm[t - off] : 0;
        __syncthreads();
        sm[t] += a;
        __syncthreads();
    }
    if (t < nb) blockpart[t] = sm[t] - v;
}

__global__ __launch_bounds__(256) void scanC(
    int* __restrict__ rowptr, const int* __restrict__ blockpart,
    int* __restrict__ cursor, int n, int total)
{
    int i = blockIdx.x * 256 + threadIdx.x;
    if (i < n) {
        int r = rowptr[i] + blockpart[i >> 10];
        rowptr[i] = r;
        cursor[i] = r;
    }
    if (i == 0) rowptr[n] = total;
}

__global__ __launch_bounds__(256) void fill_kernel(
    const int* __restrict__ rows, const int* __restrict__ cols,
    const float* __restrict__ vals, int* __restrict__ cursor,
    int2* __restrict__ csr, int ne, int nu)
{
    int e = blockIdx.x * 256 + threadIdx.x;
    if (e >= ne) return;
    int r = rows[e], c = cols[e];
    int vb = __float_as_int(vals[e]);
    int p = atomicAdd(&cursor[r], 1);
    csr[p] = make_int2(c, vb);
    int q = atomicAdd(&cursor[nu + c], 1);
    csr[q] = make_int2(r, vb);
}

// ============ gather SpMM (bf16 sources) + residual + LayerNorm ============
// One wave per destination row. Row = 64 uints (bf16x2). lane loads 1 uint/edge.
template<bool RES_BF, bool OUT_BF>
__global__ __launch_bounds__(256) void gather_ln_k(
    const uint* __restrict__ srcU,   // bf16 table gathered by user rows
    const uint* __restrict__ srcI,   // bf16 table gathered by item rows
    const void* __restrict__ resU, const void* __restrict__ resI,
    void* __restrict__ outU, void* __restrict__ outI,
    const int* __restrict__ rowptr, const int2* __restrict__ csr,
    const float* __restrict__ gamma, const float* __restrict__ beta,
    int nu, int N)
{
    int w = blockIdx.x * 4 + (threadIdx.x >> 6);
    if (w >= N) return;
    int lane = threadIdx.x & 63;

    const uint* tbl;
    const void* res;
    void* out;
    if (w < nu) {
        tbl = srcU;
        res = RES_BF ? (const void*)((const uint*)resU + (ll)w * 64)
                     : (const void*)((const float2*)resU + (ll)w * 64);
        out = OUT_BF ? (void*)((uint*)outU + (ll)w * 64)
                     : (void*)((float2*)outU + (ll)w * 64);
    } else {
        int k = w - nu;
        tbl = srcI;
        res = RES_BF ? (const void*)((const uint*)resI + (ll)k * 64)
                     : (const void*)((const float2*)resI + (ll)k * 64);
        out = OUT_BF ? (void*)((uint*)outI + (ll)k * 64)
                     : (void*)((float2*)outI + (ll)k * 64);
    }

    int start = rowptr[w];
    int end   = rowptr[w + 1];

    float ax = 0.0f, ay = 0.0f;
    int j = start;
    for (; j + 3 < end; j += 4) {
        int2 e0 = csr[j], e1 = csr[j + 1], e2 = csr[j + 2], e3 = csr[j + 3];
        uint x0 = tbl[((uint)e0.x << 6) + lane];
        uint x1 = tbl[((uint)e1.x << 6) + lane];
        uint x2 = tbl[((uint)e2.x << 6) + lane];
        uint x3 = tbl[((uint)e3.x << 6) + lane];
        float v0 = __int_as_float(e0.y), v1 = __int_as_float(e1.y);
        float v2 = __int_as_float(e2.y), v3 = __int_as_float(e3.y);
        ax += v0 * unpack_lo(x0); ay += v0 * unpack_hi(x0);
        ax += v1 * unpack_lo(x1); ay += v1 * unpack_hi(x1);
        ax += v2 * unpack_lo(x2); ay += v2 * unpack_hi(x2);
        ax += v3 * unpack_lo(x3); ay += v3 * unpack_hi(x3);
    }
    for (; j < end; j++) {
        int2 e0 = csr[j];
        uint x0 = tbl[((uint)e0.x << 6) + lane];
        float v0 = __int_as_float(e0.y);
        ax += v0 * unpack_lo(x0); ay += v0 * unpack_hi(x0);
    }

    // residual
    if (RES_BF) {
        uint r = ((const uint*)res)[lane];
        ax += unpack_lo(r); ay += unpack_hi(r);
    } else {
        float2 r = ((const float2*)res)[lane];
        ax += r.x; ay += r.y;
    }

    float s  = ax + ay;
    float ss = ax * ax + ay * ay;
#pragma unroll
    for (int off = 32; off > 0; off >>= 1) {
        s  += __shfl_xor(s, off, 64);
        ss += __shfl_xor(ss, off, 64);
    }
    float m   = s * (1.0f / 128.0f);
    float var = ss * (1.0f / 128.0f) - m * m;
    float inv = rsqrtf(var + EPS);

    float2 gm = ((const float2*)gamma)[lane];
    float2 bt = ((const float2*)beta)[lane];
    float ox = gm.x * (ax - m) * inv + bt.x;
    float oy = gm.y * (ay - m) * inv + bt.y;

    if (OUT_BF) {
        ((uint*)out)[lane] = pack2(ox, oy);
    } else {
        ((float2*)out)[lane] = make_float2(ox, oy);
    }
}

extern "C" void kernel_launch(void* const* d_in, const int* in_sizes, int n_in,
                              void* d_out, int out_size, void* d_ws, size_t ws_size,
                              hipStream_t stream)
{
    const float* user_emb = (const float*)d_in[0];
    const float* item_emb = (const float*)d_in[1];
    const float* vals     = (const float*)d_in[2];
    const float* gamma    = (const float*)d_in[3];
    const float* beta     = (const float*)d_in[4];
    const int*   rows     = (const int*)d_in[5];
    const int*   cols     = (const int*)d_in[6];

    const int nu = in_sizes[0] / 128;   // 100000
    const int ni = in_sizes[1] / 128;   // 200000
    const int ne = in_sizes[2];         // 2000000
    const int N  = nu + ni;
    const int total = 2 * ne;

    float* dout   = (float*)d_out;
    float* dout_u = dout;
    float* dout_i = dout + (ll)nu * 128;

    // bf16 input tables live in d_out until layer 2 overwrites it
    uint* bf_u = (uint*)d_out;                 // nu*64 uints
    uint* bf_i = bf_u + (ll)nu * 64;           // ni*64 uints  (total 38.4 MB of 153.6)

    // ---- workspace layout (~112.5 MB) ----
    const int Npad = ((N + 1 + 255) & ~255);
    int*  cnt       = (int*)d_ws;              // Npad
    int*  rowptr    = cnt + Npad;              // Npad (incl sentinel)
    int*  cursor    = rowptr + Npad;           // Npad
    int*  blockpart = cursor + Npad;           // 512
    int2* csr       = (int2*)(blockpart + 512);        // total entries, 32 MB
    uint* wu_out    = (uint*)(csr + total);            // nu*64, 25.6 MB
    uint* wi_out    = wu_out + (ll)nu * 64;            // ni*64, 51.2 MB

    const int eb  = (ne + 255) / 256;
    const int nbA = (N + 1023) / 1024;
    const int nbC = (N + 255) / 256;
    const int totT = (nu + ni) * 16;           // bf16-convert threads (8 elems each)

    // ---- convert inputs to bf16 (into d_out) ----
    to_bf16<<<(totT + 255) / 256, 256, 0, stream>>>(user_emb, item_emb,
                                                    (uint4*)bf_u, nu * 16, totT);

    // ---- build CSR ----
    hipMemsetAsync(cnt, 0, (size_t)N * sizeof(int), stream);
    count_kernel<<<eb, 256, 0, stream>>>(rows, cols, cnt, ne, nu);
    scanA<<<nbA, 256, 0, stream>>>(cnt, rowptr, blockpart, N);
    scanB<<<1, 512, 0, stream>>>(blockpart, nbA);
    scanC<<<nbC, 256, 0, stream>>>(rowptr, blockpart, cursor, N, total);
    fill_kernel<<<eb, 256, 0, stream>>>(rows, cols, vals, cursor, csr, ne, nu);

    const int gblocks = (N + 3) / 4;

    // ---- layer 1: gather bf16 tables (d_out), f32 residual (inputs),
    //      write bf16 layer-1 outputs (ws) ----
    gather_ln_k<false, true><<<gblocks, 256, 0, stream>>>(
        bf_i, bf_u,                 // user rows gather items; item rows gather users
        user_emb, item_emb,         // f32 residuals
        wu_out, wi_out,             // bf16 outs
        rowptr, csr, gamma, beta, nu, N);

    // ---- layer 2: gather bf16 L1 outs (ws), bf16 residuals (ws),
    //      write f32 finals (d_out) ----
    gather_ln_k<true, false><<<gblocks, 256, 0, stream>>>(
        wi_out, wu_out,
        wu_out, wi_out,
        dout_u, dout_i,
        rowptr, csr, gamma, beta, nu, N);
}

// Round 4
// 990.271 us; speedup vs baseline: 13.8504x; 1.2693x over previous
//
#include <hip/hip_runtime.h>

#define EPS 1e-5f
typedef long long ll;
typedef unsigned int uint;

__device__ __forceinline__ uint bf_round(float x) {
    uint u = __float_as_uint(x);
    return (u + 0x7FFFu + ((u >> 16) & 1u)) >> 16;
}
__device__ __forceinline__ uint pack2(float a, float b) {
    return bf_round(a) | (bf_round(b) << 16);
}
__device__ __forceinline__ float unpack_lo(uint u) { return __uint_as_float(u << 16); }
__device__ __forceinline__ float unpack_hi(uint u) { return __uint_as_float(u & 0xFFFF0000u); }

// ---- convert f32 tables -> bf16x2 packed (user then item, contiguous) ----
__global__ __launch_bounds__(256) void to_bf16(
    const float* __restrict__ ue, const float* __restrict__ ie,
    uint4* __restrict__ out, int nuT, int totT)
{
    int t = blockIdx.x * 256 + threadIdx.x;
    if (t >= totT) return;
    const float4* src = (t < nuT) ? (const float4*)(ue + (ll)t * 8)
                                  : (const float4*)(ie + (ll)(t - nuT) * 8);
    float4 f0 = src[0], f1 = src[1];
    uint4 q;
    q.x = pack2(f0.x, f0.y); q.y = pack2(f0.z, f0.w);
    q.z = pack2(f1.x, f1.y); q.w = pack2(f1.z, f1.w);
    out[t] = q;
}

// ============ CSR build ============
// count + capture rank (= old count) per edge endpoint. Coalesced rank writes.
__global__ __launch_bounds__(256) void count_rank(
    const int* __restrict__ rows, const int* __restrict__ cols,
    int* __restrict__ cnt, int* __restrict__ rank_r, int* __restrict__ rank_c,
    int ne, int nu)
{
    int e = blockIdx.x * 256 + threadIdx.x;
    if (e >= ne) return;
    rank_r[e] = atomicAdd(&cnt[rows[e]], 1);
    rank_c[e] = atomicAdd(&cnt[nu + cols[e]], 1);
}

__global__ __launch_bounds__(256) void scanA(
    const int* __restrict__ cnt, int* __restrict__ rowptr,
    int* __restrict__ blockpart, int n)
{
    __shared__ int sm[256];
    int t = threadIdx.x;
    int base = blockIdx.x * 1024 + t * 4;
    int v[4]; int s = 0;
#pragma unroll
    for (int k = 0; k < 4; k++) {
        int i = base + k;
        v[k] = (i < n) ? cnt[i] : 0;
        s += v[k];
    }
    sm[t] = s; __syncthreads();
    for (int off = 1; off < 256; off <<= 1) {
        int a = (t >= off) ? sm[t - off] : 0;
        __syncthreads();
        sm[t] += a;
        __syncthreads();
    }
    int excl = sm[t] - s;
    if (t == 255) blockpart[blockIdx.x] = sm[255];
    int run = excl;
#pragma unroll
    for (int k = 0; k < 4; k++) {
        int i = base + k;
        if (i < n) rowptr[i] = run;
        run += v[k];
    }
}

__global__ __launch_bounds__(512) void scanB(int* __restrict__ blockpart, int nb)
{
    __shared__ int sm[512];
    int t = threadIdx.x;
    int v = (t < nb) ? blockpart[t] : 0;
    sm[t] = v; __syncthreads();
    for (int off = 1; off < 512; off <<= 1) {
        int a = (t >= off) ? sm[t - off] : 0;
        __syncthreads();
        sm[t] += a;
        __syncthreads();
    }
    if (t < nb) blockpart[t] = sm[t] - v;
}

__global__ __launch_bounds__(256) void scanC(
    int* __restrict__ rowptr, const int* __restrict__ blockpart, int n, int total)
{
    int i = blockIdx.x * 256 + threadIdx.x;
    if (i < n) rowptr[i] += blockpart[i >> 10];
    if (i == 0) rowptr[n] = total;
}

// atomic-free fill: slot = rowptr[bucket] + precomputed rank.
__global__ __launch_bounds__(256) void fill_kernel(
    const int* __restrict__ rows, const int* __restrict__ cols,
    const float* __restrict__ vals,
    const int* __restrict__ rowptr,
    const int* __restrict__ rank_r, const int* __restrict__ rank_c,
    int2* __restrict__ csr, int ne, int nu)
{
    int e = blockIdx.x * 256 + threadIdx.x;
    if (e >= ne) return;
    int r = rows[e], c = cols[e];
    int vb = __float_as_int(vals[e]);
    int p = rowptr[r] + rank_r[e];
    csr[p] = make_int2(c, vb);
    int q = rowptr[nu + c] + rank_c[e];
    csr[q] = make_int2(r, vb);
}

// ============ gather SpMM (bf16 sources) + residual + LayerNorm ============
// One wave per dst row; 32 lanes x 8B cover the 256B row; 2 edges per iter.
template<bool RES_BF, bool OUT_BF>
__global__ __launch_bounds__(256) void gather_ln_k(
    const uint* __restrict__ srcU,   // bf16 table gathered by user rows
    const uint* __restrict__ srcI,   // bf16 table gathered by item rows
    const void* __restrict__ resU, const void* __restrict__ resI,
    void* __restrict__ outU, void* __restrict__ outI,
    const int* __restrict__ rowptr, const int2* __restrict__ csr,
    const float* __restrict__ gamma, const float* __restrict__ beta,
    int nu, int N)
{
    int w = blockIdx.x * 4 + (threadIdx.x >> 6);
    if (w >= N) return;
    int lane = threadIdx.x & 63;
    int sub  = lane >> 5;    // which edge of the pair
    int l32  = lane & 31;    // 8B chunk within row (channels l32*4 .. +3)

    const uint2* tbl;
    const void* res;
    void* out;
    if (w < nu) {
        tbl = (const uint2*)srcU;
        res = RES_BF ? (const void*)((const uint2*)resU + (ll)w * 32)
                     : (const void*)((const float4*)resU + (ll)w * 32);
        out = OUT_BF ? (void*)((uint2*)outU + (ll)w * 32)
                     : (void*)((float4*)outU + (ll)w * 32);
    } else {
        int k = w - nu;
        tbl = (const uint2*)srcI;
        res = RES_BF ? (const void*)((const uint2*)resI + (ll)k * 32)
                     : (const void*)((const float4*)resI + (ll)k * 32);
        out = OUT_BF ? (void*)((uint2*)outI + (ll)k * 32)
                     : (void*)((float4*)outI + (ll)k * 32);
    }

    int start = rowptr[w];
    int end   = rowptr[w + 1];

    float a0 = 0.f, a1 = 0.f, a2 = 0.f, a3 = 0.f;
    int j = start + sub;
    // unrolled by 2 wave-iterations (4 edges in flight)
    for (; j + 2 < end; j += 4) {
        int2 e0 = csr[j];
        int2 e1 = csr[j + 2];
        uint2 x0 = tbl[((uint)e0.x << 5) + l32];
        uint2 x1 = tbl[((uint)e1.x << 5) + l32];
        float v0 = __int_as_float(e0.y);
        float v1 = __int_as_float(e1.y);
        a0 += v0 * unpack_lo(x0.x); a1 += v0 * unpack_hi(x0.x);
        a2 += v0 * unpack_lo(x0.y); a3 += v0 * unpack_hi(x0.y);
        a0 += v1 * unpack_lo(x1.x); a1 += v1 * unpack_hi(x1.x);
        a2 += v1 * unpack_lo(x1.y); a3 += v1 * unpack_hi(x1.y);
    }
    if (j < end) {
        int2 e0 = csr[j];
        uint2 x0 = tbl[((uint)e0.x << 5) + l32];
        float v0 = __int_as_float(e0.y);
        a0 += v0 * unpack_lo(x0.x); a1 += v0 * unpack_hi(x0.x);
        a2 += v0 * unpack_lo(x0.y); a3 += v0 * unpack_hi(x0.y);
    }

    // merge the two edge subgroups (lanes l and l+32 hold same channels)
    a0 += __shfl_xor(a0, 32, 64);
    a1 += __shfl_xor(a1, 32, 64);
    a2 += __shfl_xor(a2, 32, 64);
    a3 += __shfl_xor(a3, 32, 64);

    // residual (same address in both halves -> broadcast)
    if (RES_BF) {
        uint2 r = ((const uint2*)res)[l32];
        a0 += unpack_lo(r.x); a1 += unpack_hi(r.x);
        a2 += unpack_lo(r.y); a3 += unpack_hi(r.y);
    } else {
        float4 r = ((const float4*)res)[l32];
        a0 += r.x; a1 += r.y; a2 += r.z; a3 += r.w;
    }

    // LN reduction: butterfly over all 64 lanes double-counts (dup halves) -> /256
    float s  = a0 + a1 + a2 + a3;
    float ss = a0 * a0 + a1 * a1 + a2 * a2 + a3 * a3;
#pragma unroll
    for (int off = 32; off > 0; off >>= 1) {
        s  += __shfl_xor(s, off, 64);
        ss += __shfl_xor(ss, off, 64);
    }
    float m   = s * (1.0f / 256.0f);
    float var = ss * (1.0f / 256.0f) - m * m;
    float inv = rsqrtf(var + EPS);

    float4 gm = ((const float4*)gamma)[l32];
    float4 bt = ((const float4*)beta)[l32];
    float o0 = gm.x * (a0 - m) * inv + bt.x;
    float o1 = gm.y * (a1 - m) * inv + bt.y;
    float o2 = gm.z * (a2 - m) * inv + bt.z;
    float o3 = gm.w * (a3 - m) * inv + bt.w;

    if (sub == 0) {
        if (OUT_BF) {
            uint2 q; q.x = pack2(o0, o1); q.y = pack2(o2, o3);
            ((uint2*)out)[l32] = q;
        } else {
            ((float4*)out)[l32] = make_float4(o0, o1, o2, o3);
        }
    }
}

extern "C" void kernel_launch(void* const* d_in, const int* in_sizes, int n_in,
                              void* d_out, int out_size, void* d_ws, size_t ws_size,
                              hipStream_t stream)
{
    const float* user_emb = (const float*)d_in[0];
    const float* item_emb = (const float*)d_in[1];
    const float* vals     = (const float*)d_in[2];
    const float* gamma    = (const float*)d_in[3];
    const float* beta     = (const float*)d_in[4];
    const int*   rows     = (const int*)d_in[5];
    const int*   cols     = (const int*)d_in[6];

    const int nu = in_sizes[0] / 128;   // 100000
    const int ni = in_sizes[1] / 128;   // 200000
    const int ne = in_sizes[2];         // 2000000
    const int N  = nu + ni;
    const int total = 2 * ne;

    float* dout   = (float*)d_out;
    float* dout_u = dout;
    float* dout_i = dout + (ll)nu * 128;

    // bf16 input tables live in d_out until layer 2 overwrites it
    uint* bf_u = (uint*)d_out;                 // nu*64 uints
    uint* bf_i = bf_u + (ll)nu * 64;           // ni*64 uints

    // ---- workspace layout (~127 MB) ----
    const int Npad = ((N + 1 + 255) & ~255);
    int*  cnt       = (int*)d_ws;              // Npad
    int*  rowptr    = cnt + Npad;              // Npad (incl sentinel)
    int*  blockpart = rowptr + Npad;           // 512
    int*  rank_r    = blockpart + 512;         // ne
    int*  rank_c    = rank_r + ne;             // ne
    int2* csr       = (int2*)(rank_c + ne);            // total entries, 32 MB
    uint* wu_out    = (uint*)(csr + total);            // nu*64, 25.6 MB
    uint* wi_out    = wu_out + (ll)nu * 64;            // ni*64, 51.2 MB

    const int eb  = (ne + 255) / 256;
    const int nbA = (N + 1023) / 1024;
    const int nbC = (N + 255) / 256;
    const int totT = (nu + ni) * 16;

    // ---- convert inputs to bf16 (into d_out) ----
    to_bf16<<<(totT + 255) / 256, 256, 0, stream>>>(user_emb, item_emb,
                                                    (uint4*)bf_u, nu * 16, totT);

    // ---- build CSR (atomic-free fill via ranks) ----
    hipMemsetAsync(cnt, 0, (size_t)N * sizeof(int), stream);
    count_rank<<<eb, 256, 0, stream>>>(rows, cols, cnt, rank_r, rank_c, ne, nu);
    scanA<<<nbA, 256, 0, stream>>>(cnt, rowptr, blockpart, N);
    scanB<<<1, 512, 0, stream>>>(blockpart, nbA);
    scanC<<<nbC, 256, 0, stream>>>(rowptr, blockpart, N, total);
    fill_kernel<<<eb, 256, 0, stream>>>(rows, cols, vals, rowptr, rank_r, rank_c,
                                        csr, ne, nu);

    const int gblocks = (N + 3) / 4;

    // ---- layer 1: gather bf16 tables (d_out), f32 residual (inputs),
    //      write bf16 layer-1 outputs (ws) ----
    gather_ln_k<false, true><<<gblocks, 256, 0, stream>>>(
        bf_i, bf_u,
        user_emb, item_emb,
        wu_out, wi_out,
        rowptr, csr, gamma, beta, nu, N);

    // ---- layer 2: gather bf16 L1 outs (ws), bf16 residuals (ws),
    //      write f32 finals (d_out) ----
    gather_ln_k<true, false><<<gblocks, 256, 0, stream>>>(
        wi_out, wu_out,
        wu_out, wi_out,
        dout_u, dout_i,
        rowptr, csr, gamma, beta, nu, N);
}

// Round 5
// 919.726 us; speedup vs baseline: 14.9127x; 1.0767x over previous
//
#include <hip/hip_runtime.h>

#define EPS 1e-5f
typedef long long ll;
typedef unsigned int uint;

__device__ __forceinline__ uint bf_round(float x) {
    uint u = __float_as_uint(x);
    return (u + 0x7FFFu + ((u >> 16) & 1u)) >> 16;
}
__device__ __forceinline__ uint pack2(float a, float b) {
    return bf_round(a) | (bf_round(b) << 16);
}
__device__ __forceinline__ float unpack_lo(uint u) { return __uint_as_float(u << 16); }
__device__ __forceinline__ float unpack_hi(uint u) { return __uint_as_float(u & 0xFFFF0000u); }

// ---- fused prep: blocks [0,cb) do count+rank, blocks [cb,cb+tb) do f32->bf16 ----
__global__ __launch_bounds__(256) void prep_kernel(
    const int* __restrict__ rows, const int* __restrict__ cols,
    int* __restrict__ cnt, int* __restrict__ rank_r, int* __restrict__ rank_c,
    int ne, int nu, int cb,
    const float* __restrict__ ue, const float* __restrict__ ie,
    uint4* __restrict__ bfout, int nuT, int totT)
{
    int b = blockIdx.x;
    if (b < cb) {
        int e = b * 256 + threadIdx.x;
        if (e < ne) {
            rank_r[e] = atomicAdd(&cnt[rows[e]], 1);
            rank_c[e] = atomicAdd(&cnt[nu + cols[e]], 1);
        }
    } else {
        int t = (b - cb) * 256 + threadIdx.x;
        if (t < totT) {
            const float4* src = (t < nuT) ? (const float4*)(ue + (ll)t * 8)
                                          : (const float4*)(ie + (ll)(t - nuT) * 8);
            float4 f0 = src[0], f1 = src[1];
            uint4 q;
            q.x = pack2(f0.x, f0.y); q.y = pack2(f0.z, f0.w);
            q.z = pack2(f1.x, f1.y); q.w = pack2(f1.z, f1.w);
            bfout[t] = q;
        }
    }
}

// ============ scans ============
__global__ __launch_bounds__(256) void scanA(
    const int* __restrict__ cnt, int* __restrict__ rowptr,
    int* __restrict__ blockpart, int n)
{
    __shared__ int sm[256];
    int t = threadIdx.x;
    int base = blockIdx.x * 1024 + t * 4;
    int v[4]; int s = 0;
#pragma unroll
    for (int k = 0; k < 4; k++) {
        int i = base + k;
        v[k] = (i < n) ? cnt[i] : 0;
        s += v[k];
    }
    sm[t] = s; __syncthreads();
    for (int off = 1; off < 256; off <<= 1) {
        int a = (t >= off) ? sm[t - off] : 0;
        __syncthreads();
        sm[t] += a;
        __syncthreads();
    }
    int excl = sm[t] - s;
    if (t == 255) blockpart[blockIdx.x] = sm[255];
    int run = excl;
#pragma unroll
    for (int k = 0; k < 4; k++) {
        int i = base + k;
        if (i < n) rowptr[i] = run;
        run += v[k];
    }
}

__global__ __launch_bounds__(512) void scanB(int* __restrict__ blockpart, int nb)
{
    __shared__ int sm[512];
    int t = threadIdx.x;
    int v = (t < nb) ? blockpart[t] : 0;
    sm[t] = v; __syncthreads();
    for (int off = 1; off < 512; off <<= 1) {
        int a = (t >= off) ? sm[t - off] : 0;
        __syncthreads();
        sm[t] += a;
        __syncthreads();
    }
    if (t < nb) blockpart[t] = sm[t] - v;
}

__global__ __launch_bounds__(256) void scanC(
    int* __restrict__ rowptr, const int* __restrict__ blockpart, int n, int total)
{
    int i = blockIdx.x * 256 + threadIdx.x;
    if (i < n) rowptr[i] += blockpart[i >> 10];
    if (i == 0) rowptr[n] = total;
}

// atomic-free fill: slot = rowptr[bucket] + precomputed rank.
__global__ __launch_bounds__(256) void fill_kernel(
    const int* __restrict__ rows, const int* __restrict__ cols,
    const float* __restrict__ vals,
    const int* __restrict__ rowptr,
    const int* __restrict__ rank_r, const int* __restrict__ rank_c,
    int2* __restrict__ csr, int ne, int nu)
{
    int e = blockIdx.x * 256 + threadIdx.x;
    if (e >= ne) return;
    int r = rows[e], c = cols[e];
    int vb = __float_as_int(vals[e]);
    int p = rowptr[r] + rank_r[e];
    csr[p] = make_int2(c, vb);
    int q = rowptr[nu + c] + rank_c[e];
    csr[q] = make_int2(r, vb);
}

// ============ gather SpMM (bf16) + residual + LayerNorm ============
// One wave per dst row. 16 lanes x 16B (uint4) cover the 256B bf16 row;
// 4 edge-subgroups -> 4 edges (1 KB) in flight per iteration; csr prefetched.
template<bool OUT_BF>
__global__ __launch_bounds__(256) void gather_ln_k(
    const uint4* __restrict__ srcU,  // table gathered by user rows
    const uint4* __restrict__ srcI,  // table gathered by item rows
    const uint4* __restrict__ resU, const uint4* __restrict__ resI, // bf16 residual
    void* __restrict__ outU, void* __restrict__ outI,
    const int* __restrict__ rowptr, const int2* __restrict__ csr,
    const float* __restrict__ gamma, const float* __restrict__ beta,
    int nu, int N)
{
    int w = blockIdx.x * 4 + (threadIdx.x >> 6);
    if (w >= N) return;
    int lane = threadIdx.x & 63;
    int sub  = lane >> 4;   // edge slot 0..3
    int l16  = lane & 15;   // 16B chunk in row -> channels l16*8 .. +7

    const uint4* tbl;
    const uint4* res;
    void* out;
    if (w < nu) {
        tbl = srcU;
        res = resU + (ll)w * 16;
        out = OUT_BF ? (void*)((uint4*)outU + (ll)w * 16)
                     : (void*)((float4*)outU + (ll)w * 32);
    } else {
        int k = w - nu;
        tbl = srcI;
        res = resI + (ll)k * 16;
        out = OUT_BF ? (void*)((uint4*)outI + (ll)k * 16)
                     : (void*)((float4*)outI + (ll)k * 32);
    }

    int start = rowptr[w];
    int end   = rowptr[w + 1];

    float a0=0.f,a1=0.f,a2=0.f,a3=0.f,a4=0.f,a5=0.f,a6=0.f,a7=0.f;

    if (start < end) {
        int i0 = start + sub;
        int2 ec = csr[i0 < end ? i0 : end - 1];
        for (int j = start; j < end; j += 4) {
            int2 en;
            int jn = j + 4;
            if (jn < end) {                       // wave-uniform branch
                int i1 = jn + sub;
                en = csr[i1 < end ? i1 : end - 1]; // prefetch next iter
            }
            float v = ((j + sub) < end) ? __int_as_float(ec.y) : 0.0f;
            uint4 q = tbl[(((uint)ec.x) << 4) + l16];
            a0 += v * unpack_lo(q.x); a1 += v * unpack_hi(q.x);
            a2 += v * unpack_lo(q.y); a3 += v * unpack_hi(q.y);
            a4 += v * unpack_lo(q.z); a5 += v * unpack_hi(q.z);
            a6 += v * unpack_lo(q.w); a7 += v * unpack_hi(q.w);
            ec = en;
        }
    }

    // merge the 4 edge-subgroups (lanes l16, +16, +32, +48 hold same channels)
#define MRG(x) x += __shfl_xor(x, 16, 64); x += __shfl_xor(x, 32, 64)
    MRG(a0); MRG(a1); MRG(a2); MRG(a3); MRG(a4); MRG(a5); MRG(a6); MRG(a7);
#undef MRG

    // residual (bf16 row, broadcast across subgroups)
    uint4 r = res[l16];
    a0 += unpack_lo(r.x); a1 += unpack_hi(r.x);
    a2 += unpack_lo(r.y); a3 += unpack_hi(r.y);
    a4 += unpack_lo(r.z); a5 += unpack_hi(r.z);
    a6 += unpack_lo(r.w); a7 += unpack_hi(r.w);

    // LN stats: sum over the 16-lane group (channels unique within group)
    float s  = a0+a1+a2+a3+a4+a5+a6+a7;
    float ss = a0*a0+a1*a1+a2*a2+a3*a3+a4*a4+a5*a5+a6*a6+a7*a7;
#pragma unroll
    for (int off = 8; off > 0; off >>= 1) {
        s  += __shfl_xor(s, off, 64);
        ss += __shfl_xor(ss, off, 64);
    }
    float m   = s * (1.0f / 128.0f);
    float var = ss * (1.0f / 128.0f) - m * m;
    float inv = rsqrtf(var + EPS);

    float4 g0 = ((const float4*)gamma)[l16 * 2];
    float4 g1 = ((const float4*)gamma)[l16 * 2 + 1];
    float4 b0 = ((const float4*)beta)[l16 * 2];
    float4 b1 = ((const float4*)beta)[l16 * 2 + 1];
    float o0 = g0.x * (a0 - m) * inv + b0.x;
    float o1 = g0.y * (a1 - m) * inv + b0.y;
    float o2 = g0.z * (a2 - m) * inv + b0.z;
    float o3 = g0.w * (a3 - m) * inv + b0.w;
    float o4 = g1.x * (a4 - m) * inv + b1.x;
    float o5 = g1.y * (a5 - m) * inv + b1.y;
    float o6 = g1.z * (a6 - m) * inv + b1.z;
    float o7 = g1.w * (a7 - m) * inv + b1.w;

    if (sub == 0) {
        if (OUT_BF) {
            uint4 q;
            q.x = pack2(o0, o1); q.y = pack2(o2, o3);
            q.z = pack2(o4, o5); q.w = pack2(o6, o7);
            ((uint4*)out)[l16] = q;
        } else {
            ((float4*)out)[l16 * 2]     = make_float4(o0, o1, o2, o3);
            ((float4*)out)[l16 * 2 + 1] = make_float4(o4, o5, o6, o7);
        }
    }
}

extern "C" void kernel_launch(void* const* d_in, const int* in_sizes, int n_in,
                              void* d_out, int out_size, void* d_ws, size_t ws_size,
                              hipStream_t stream)
{
    const float* user_emb = (const float*)d_in[0];
    const float* item_emb = (const float*)d_in[1];
    const float* vals     = (const float*)d_in[2];
    const float* gamma    = (const float*)d_in[3];
    const float* beta     = (const float*)d_in[4];
    const int*   rows     = (const int*)d_in[5];
    const int*   cols     = (const int*)d_in[6];

    const int nu = in_sizes[0] / 128;   // 100000
    const int ni = in_sizes[1] / 128;   // 200000
    const int ne = in_sizes[2];         // 2000000
    const int N  = nu + ni;
    const int total = 2 * ne;

    float* dout   = (float*)d_out;
    float* dout_u = dout;
    float* dout_i = dout + (ll)nu * 128;

    // bf16 input tables live in d_out until layer 2 overwrites it
    uint* bf_u = (uint*)d_out;                 // nu*64 uints (25.6 MB)
    uint* bf_i = bf_u + (ll)nu * 64;           // ni*64 uints (51.2 MB)

    // ---- workspace layout (~127 MB) ----
    const int Npad = ((N + 1 + 255) & ~255);
    int*  cnt       = (int*)d_ws;              // Npad
    int*  rowptr    = cnt + Npad;              // Npad (incl sentinel)
    int*  blockpart = rowptr + Npad;           // 512
    int*  rank_r    = blockpart + 512;         // ne
    int*  rank_c    = rank_r + ne;             // ne
    int2* csr       = (int2*)(rank_c + ne);            // total entries, 32 MB
    uint* wu_out    = (uint*)(csr + total);            // nu*64, 25.6 MB
    uint* wi_out    = wu_out + (ll)nu * 64;            // ni*64, 51.2 MB

    const int cb   = (ne + 255) / 256;
    const int nbA  = (N + 1023) / 1024;
    const int nbC  = (N + 255) / 256;
    const int totT = (nu + ni) * 16;
    const int tb   = (totT + 255) / 256;

    // ---- CSR count/rank + bf16 conversion, fused ----
    hipMemsetAsync(cnt, 0, (size_t)N * sizeof(int), stream);
    prep_kernel<<<cb + tb, 256, 0, stream>>>(rows, cols, cnt, rank_r, rank_c,
                                             ne, nu, cb,
                                             user_emb, item_emb,
                                             (uint4*)bf_u, nu * 16, totT);
    scanA<<<nbA, 256, 0, stream>>>(cnt, rowptr, blockpart, N);
    scanB<<<1, 512, 0, stream>>>(blockpart, nbA);
    scanC<<<nbC, 256, 0, stream>>>(rowptr, blockpart, N, total);
    fill_kernel<<<cb, 256, 0, stream>>>(rows, cols, vals, rowptr, rank_r, rank_c,
                                        csr, ne, nu);

    const int gblocks = (N + 3) / 4;

    // ---- layer 1: gather bf16 input tables (d_out), bf16 residual (d_out),
    //      write bf16 layer-1 outputs (ws) ----
    gather_ln_k<true><<<gblocks, 256, 0, stream>>>(
        (const uint4*)bf_i, (const uint4*)bf_u,
        (const uint4*)bf_u, (const uint4*)bf_i,
        wu_out, wi_out,
        rowptr, csr, gamma, beta, nu, N);

    // ---- layer 2: gather bf16 L1 outs (ws), bf16 residuals (ws),
    //      write f32 finals (d_out) ----
    gather_ln_k<false><<<gblocks, 256, 0, stream>>>(
        (const uint4*)wi_out, (const uint4*)wu_out,
        (const uint4*)wu_out, (const uint4*)wi_out,
        dout_u, dout_i,
        rowptr, csr, gamma, beta, nu, N);
}